// Round 4
// baseline (2619.886 us; speedup 1.0000x reference)
//
#include <hip/hip_runtime.h>
#include <hip/hip_cooperative_groups.h>
#include <stdint.h>
#include <math.h>

namespace cg = cooperative_groups;

// Problem constants (fixed by setup_inputs: B=4, N=4096, H=2048, L=64, K=8)
constexpr int H     = 2048;
constexpr int L     = 64;
constexpr int K_SEL = 8;
constexpr int TM    = 32;     // rows per block (phase 1)
constexpr int NBLK  = 512;    // grid: 2 blocks/CU, co-resident for grid.sync
// bf16 hi/lo split noise sigma ~1e-5 per logit (dropped lo*lo + truncation terms).
// EPS = 2e-4 = 20 sigma (Hoeffding tail ~exp(-571)); n_fix ~ 131072*EPS/0.071 ~ 370 rows.
constexpr float EPS_GAP = 2e-4f;

// ws carve (byte offsets; ws >= 4.7 MB per earlier rounds)
// counts:uint[65]@0  nfix:uint@512  list:uint[16384]@1024
// Wt:float[2048*64]@66560  Whi:ushort[64*2048]@590848  Wlo:ushort[64*2048]@852992
constexpr size_t WSB_COUNTS = 0;
constexpr size_t WSB_NFIX   = 512;
constexpr size_t WSB_LIST   = 1024;
constexpr size_t WSB_WT     = 66560;
constexpr size_t WSB_WHI    = 590848;
constexpr size_t WSB_WLO    = 852992;

typedef __attribute__((ext_vector_type(8))) short bf16x8;   // 8 bf16 (4 VGPRs)
typedef __attribute__((ext_vector_type(4))) float f32x4;    // MFMA C/D frag

__device__ inline void split1(float f, unsigned short& h, unsigned short& s)
{
    unsigned int u = __float_as_uint(f);
    h = (unsigned short)(u >> 16);                              // bf16 truncate
    float hf = __uint_as_float(u & 0xffff0000u);
    s = (unsigned short)(__float_as_uint(f - hf) >> 16);        // residual, truncated
}

// ---------------------------------------------------------------- prep ----
// blocks [0,32): per 64-k chunk: W -> Wt (fp32 transpose, for fixup) and
// W -> Whi/Wlo (truncated-bf16 split, for MFMA). block 32: zero counters.
__global__ __launch_bounds__(256)
void prep(const float* __restrict__ Wr, float* __restrict__ Wt,
          unsigned short* __restrict__ Whi, unsigned short* __restrict__ Wlo,
          unsigned int* __restrict__ counts, unsigned int* __restrict__ nfix)
{
    const int t = threadIdx.x, b = blockIdx.x;
    if (b == 32) {
        if (t < L + 1) counts[t] = 0u;
        if (t == 0)    *nfix = 0u;
        return;
    }
    __shared__ float tile[64 * 65];
    const int k0 = b * 64;
    const int l = t >> 2, kq = (t & 3) * 16;
    #pragma unroll
    for (int j = 0; j < 4; ++j) {
        const int k = kq + 4 * j;
        float4 v = *(const float4*)(Wr + (size_t)l * H + k0 + k);
        tile[(k + 0) * 65 + l] = v.x;
        tile[(k + 1) * 65 + l] = v.y;
        tile[(k + 2) * 65 + l] = v.z;
        tile[(k + 3) * 65 + l] = v.w;
        ushort4 h4, l4;
        split1(v.x, h4.x, l4.x); split1(v.y, h4.y, l4.y);
        split1(v.z, h4.z, l4.z); split1(v.w, h4.w, l4.w);
        *(ushort4*)(Whi + (size_t)l * H + k0 + k) = h4;
        *(ushort4*)(Wlo + (size_t)l * H + k0 + k) = l4;
    }
    __syncthreads();
    {
        const int k = t >> 2, lq = (t & 3) * 16;
        #pragma unroll
        for (int j = 0; j < 4; ++j) {
            int l2 = lq + 4 * j;
            float4 o = make_float4(tile[k * 65 + l2], tile[k * 65 + l2 + 1],
                                   tile[k * 65 + l2 + 2], tile[k * 65 + l2 + 3]);
            *(float4*)(Wt + (size_t)(k0 + k) * L + l2) = o;
        }
    }
}

// ------------------------------------------------------- cooperative ----
// Phase 1: bf16-split MFMA GEMM (wave owns 16 rows x 64 experts) + top-9
//          select + gap gate. Barrier-free K-loop (A: global->reg->split;
//          B: pre-split bf16 from L2).
// Phase 2: fp64 exact fixup for flagged rows (wave-per-row).
// Phase 3: block 0 computes loss scalars.
__global__ __launch_bounds__(128)
void router_coop(const float* __restrict__ x, const float* __restrict__ bias,
                 const unsigned char* __restrict__ am,
                 const unsigned short* __restrict__ Whi,
                 const unsigned short* __restrict__ Wlo,
                 const float* __restrict__ Wt,
                 float* __restrict__ out_sel, float* __restrict__ out_probs,
                 unsigned int* __restrict__ counts, unsigned int* __restrict__ nfix,
                 unsigned int* __restrict__ list, float* __restrict__ out_scal)
{
    cg::grid_group grid = cg::this_grid();

    __shared__ float lg[TM][L + 1];
    __shared__ float bs[L];
    __shared__ unsigned int cnt[L + 1];

    const int t = threadIdx.x, b = blockIdx.x;
    const int lane = t & 63, w = t >> 6;          // 2 waves/block
    const int R0 = b * TM;

    if (t < L) bs[t] = bias[t];
    if (t < L + 1) cnt[t] = 0;

    // ---------------- phase 1: GEMM ----------------
    const int m  = lane & 15;          // row within 16-tile / expert within col-tile
    const int kq = (lane >> 4) * 8;    // lane's k offset within a 32-k step
    const float* xrow = x + (size_t)(R0 + 16 * w + m) * H + kq;
    const unsigned short* bhb = Whi + (size_t)m * H + kq;
    const unsigned short* blb = Wlo + (size_t)m * H + kq;

    f32x4 acc[4];
    #pragma unroll
    for (int tl = 0; tl < 4; ++tl)
        #pragma unroll
        for (int r = 0; r < 4; ++r) acc[tl][r] = 0.f;

    float4 a0[2], a1[2];
    bf16x8 bh[2][4], bl[2][4];

    // ping-pong prefetch (no barriers -> loads pipeline across iterations)
    a0[0] = *(const float4*)(xrow);
    a1[0] = *(const float4*)(xrow + 4);
    #pragma unroll
    for (int tl = 0; tl < 4; ++tl) {
        bh[0][tl] = *(const bf16x8*)(bhb + (size_t)tl * 16 * H);
        bl[0][tl] = *(const bf16x8*)(blb + (size_t)tl * 16 * H);
    }

    for (int s = 0; s < H / 32; ++s) {
        const int cur = s & 1, nxt = cur ^ 1;
        if (s + 1 < H / 32) {
            const int k = (s + 1) * 32;
            a0[nxt] = *(const float4*)(xrow + k);
            a1[nxt] = *(const float4*)(xrow + k + 4);
            #pragma unroll
            for (int tl = 0; tl < 4; ++tl) {
                bh[nxt][tl] = *(const bf16x8*)(bhb + (size_t)tl * 16 * H + k);
                bl[nxt][tl] = *(const bf16x8*)(blb + (size_t)tl * 16 * H + k);
            }
        }
        // split A into hi/lo bf16
        bf16x8 ah, al;
        {
            float f[8] = {a0[cur].x, a0[cur].y, a0[cur].z, a0[cur].w,
                          a1[cur].x, a1[cur].y, a1[cur].z, a1[cur].w};
            #pragma unroll
            for (int i = 0; i < 8; ++i) {
                unsigned int u = __float_as_uint(f[i]);
                ah[i] = (short)(u >> 16);
                float hf = __uint_as_float(u & 0xffff0000u);
                al[i] = (short)(__float_as_uint(f[i] - hf) >> 16);
            }
        }
        // 3-product split MFMA; 4 independent acc chains give ILP
        #pragma unroll
        for (int tl = 0; tl < 4; ++tl) {
            acc[tl] = __builtin_amdgcn_mfma_f32_16x16x32_bf16(ah, bh[cur][tl], acc[tl], 0, 0, 0);
            acc[tl] = __builtin_amdgcn_mfma_f32_16x16x32_bf16(al, bh[cur][tl], acc[tl], 0, 0, 0);
            acc[tl] = __builtin_amdgcn_mfma_f32_16x16x32_bf16(ah, bl[cur][tl], acc[tl], 0, 0, 0);
        }
    }

    // C/D layout: col = lane&15, row = (lane>>4)*4 + reg  [m89-verified]
    #pragma unroll
    for (int tl = 0; tl < 4; ++tl)
        #pragma unroll
        for (int r = 0; r < 4; ++r)
            lg[16 * w + (lane >> 4) * 4 + r][16 * tl + (lane & 15)] = acc[tl][r];
    __syncthreads();

    if (t < TM) {
        const int grow = R0 + t;
        unsigned long long chosen = 0ull;
        int idx[K_SEL];
        float prev = 0.f, gmin = INFINITY;
        for (int kk = 0; kk < K_SEL + 1; ++kk) {   // 9 rounds: need gap rank8->rank9
            float best = -INFINITY; int bi = 0;
            for (int l = 0; l < L; ++l) {
                if ((chosen >> l) & 1ull) continue;
                float v = lg[t][l] + bs[l];        // strict '>' == jax top_k tie-break
                if (v > best) { best = v; bi = l; }
            }
            if (kk > 0) gmin = fminf(gmin, prev - best);
            prev = best;
            if (kk < K_SEL) { chosen |= 1ull << bi; idx[kk] = bi; }
        }

        if (gmin < EPS_GAP) {
            unsigned int p = atomicAdd(nfix, 1u);
            __hip_atomic_store(&list[p], (unsigned int)grow,
                               __ATOMIC_RELAXED, __HIP_MEMORY_SCOPE_AGENT);
        } else {
            float zv[K_SEL], mx = -INFINITY;
            #pragma unroll
            for (int kk = 0; kk < K_SEL; ++kk) { zv[kk] = lg[t][idx[kk]]; mx = fmaxf(mx, zv[kk]); }
            float e[K_SEL], ssum = 0.f;
            #pragma unroll
            for (int kk = 0; kk < K_SEL; ++kk) { e[kk] = expf(zv[kk] - mx); ssum += e[kk]; }
            #pragma unroll
            for (int kk = 0; kk < K_SEL; ++kk) {
                out_sel[(size_t)grow * K_SEL + kk]   = (float)idx[kk];
                out_probs[(size_t)grow * K_SEL + kk] = e[kk] / ssum;
            }
            if (am[grow]) {
                atomicAdd(&cnt[L], 1u);
                #pragma unroll
                for (int kk = 0; kk < K_SEL; ++kk) atomicAdd(&cnt[idx[kk]], 1u);
            }
        }
    }
    __syncthreads();
    if (t < L + 1 && cnt[t]) atomicAdd(&counts[t], cnt[t]);

    __threadfence();
    grid.sync();

    // ---------------- phase 2: fp64 fixup ----------------
    {
        const int wid = (b << 1) | w;
        const int nw  = NBLK * 2;
        const int n   = (int)__hip_atomic_load(nfix, __ATOMIC_RELAXED, __HIP_MEMORY_SCOPE_AGENT);
        const double blv = (double)bias[lane];

        for (int i = wid; i < n; i += nw) {
            const int row = (int)__hip_atomic_load(&list[i], __ATOMIC_RELAXED,
                                                   __HIP_MEMORY_SCOPE_AGENT);
            const float* xr = x + (size_t)row * H;
            double A0 = 0.0, A1 = 0.0, A2 = 0.0, A3 = 0.0;
            #pragma unroll 2
            for (int k = 0; k < H; k += 16) {
                float4 x0 = *(const float4*)(xr + k);
                float4 x1 = *(const float4*)(xr + k + 4);
                float4 x2 = *(const float4*)(xr + k + 8);
                float4 x3 = *(const float4*)(xr + k + 12);
                A0 = fma((double)x0.x, (double)Wt[(k +  0) * L + lane], A0);
                A1 = fma((double)x0.y, (double)Wt[(k +  1) * L + lane], A1);
                A2 = fma((double)x0.z, (double)Wt[(k +  2) * L + lane], A2);
                A3 = fma((double)x0.w, (double)Wt[(k +  3) * L + lane], A3);
                A0 = fma((double)x1.x, (double)Wt[(k +  4) * L + lane], A0);
                A1 = fma((double)x1.y, (double)Wt[(k +  5) * L + lane], A1);
                A2 = fma((double)x1.z, (double)Wt[(k +  6) * L + lane], A2);
                A3 = fma((double)x1.w, (double)Wt[(k +  7) * L + lane], A3);
                A0 = fma((double)x2.x, (double)Wt[(k +  8) * L + lane], A0);
                A1 = fma((double)x2.y, (double)Wt[(k +  9) * L + lane], A1);
                A2 = fma((double)x2.z, (double)Wt[(k + 10) * L + lane], A2);
                A3 = fma((double)x2.w, (double)Wt[(k + 11) * L + lane], A3);
                A0 = fma((double)x3.x, (double)Wt[(k + 12) * L + lane], A0);
                A1 = fma((double)x3.y, (double)Wt[(k + 13) * L + lane], A1);
                A2 = fma((double)x3.z, (double)Wt[(k + 14) * L + lane], A2);
                A3 = fma((double)x3.w, (double)Wt[(k + 15) * L + lane], A3);
            }
            double accd = (A0 + A1) + (A2 + A3);

            double v = accd + blv;
            int    widx[K_SEL];
            double wlog[K_SEL];
            #pragma unroll
            for (int kk = 0; kk < K_SEL; ++kk) {
                double mv = v; int mi = lane;
                #pragma unroll
                for (int off = 32; off; off >>= 1) {
                    double ov = __shfl_xor(mv, off);
                    int    oi = __shfl_xor(mi, off);
                    if (ov > mv || (ov == mv && oi < mi)) { mv = ov; mi = oi; }
                }
                widx[kk] = mi;
                wlog[kk] = __shfl(accd, mi);
                if (lane == mi) v = -INFINITY;
            }

            double mx = -INFINITY;
            #pragma unroll
            for (int kk = 0; kk < K_SEL; ++kk) mx = fmax(mx, wlog[kk]);
            float e[K_SEL], ssum = 0.f;
            #pragma unroll
            for (int kk = 0; kk < K_SEL; ++kk) { e[kk] = expf((float)(wlog[kk] - mx)); ssum += e[kk]; }

            if (lane < K_SEL) {
                out_sel[(size_t)row * K_SEL + lane]   = (float)widx[lane];
                out_probs[(size_t)row * K_SEL + lane] = e[lane] / ssum;
            }
            if (am[row]) {
                if (lane < K_SEL)  atomicAdd(&counts[widx[lane]], 1u);
                if (lane == K_SEL) atomicAdd(&counts[L], 1u);
            }
        }
    }

    __threadfence();
    grid.sync();

    // ---------------- phase 3: finalize (block 0, wave 0) ----------------
    if (b == 0 && w == 0) {
        unsigned int cl = __hip_atomic_load(&counts[lane], __ATOMIC_RELAXED,
                                            __HIP_MEMORY_SCOPE_AGENT);
        unsigned int ca = __hip_atomic_load(&counts[L], __ATOMIC_RELAXED,
                                            __HIP_MEMORY_SCOPE_AGENT);
        const float denom = (float)ca * (float)K_SEL;
        const float f = (float)cl / denom;
        float d  = f - 1.0f / (float)L;
        float sq = d * d;
        #pragma unroll
        for (int o = 32; o > 0; o >>= 1) {
            sq += __shfl_down(sq, o);
            d = fmaxf(d, __shfl_down(d, o));
        }
        if (lane == 0) {
            out_scal[0] = (float)L * sq;  // load_balance_loss
            out_scal[1] = (float)L * d;   // max_vio
        }
    }
}

extern "C" void kernel_launch(void* const* d_in, const int* in_sizes, int n_in,
                              void* d_out, int out_size, void* d_ws, size_t ws_size,
                              hipStream_t stream)
{
    const float* x          = (const float*)d_in[0];
    const float* Wr         = (const float*)d_in[1];
    const float* bias       = (const float*)d_in[2];
    const unsigned char* am = (const unsigned char*)d_in[3];
    float* out = (float*)d_out;
    char*  wsb = (char*)d_ws;

    const int rows = in_sizes[3];  // B*N = 16384

    float* out_sel   = out;
    float* out_probs = out + (size_t)rows * K_SEL;
    float* out_scal  = out + (size_t)rows * K_SEL * 2;

    unsigned int*   counts = (unsigned int*)(wsb + WSB_COUNTS);
    unsigned int*   nfix   = (unsigned int*)(wsb + WSB_NFIX);
    unsigned int*   list   = (unsigned int*)(wsb + WSB_LIST);
    float*          Wt     = (float*)(wsb + WSB_WT);
    unsigned short* Whi    = (unsigned short*)(wsb + WSB_WHI);
    unsigned short* Wlo    = (unsigned short*)(wsb + WSB_WLO);

    hipLaunchKernelGGL(prep, dim3(33), dim3(256), 0, stream, Wr, Wt, Whi, Wlo, counts, nfix);

    void* args[] = { (void*)&x, (void*)&bias, (void*)&am, (void*)&Whi, (void*)&Wlo,
                     (void*)&Wt, (void*)&out_sel, (void*)&out_probs, (void*)&counts,
                     (void*)&nfix, (void*)&list, (void*)&out_scal };
    hipLaunchCooperativeKernel((void*)router_coop, dim3(NBLK), dim3(128), args, 0, stream);
}

// Round 5
// 545.275 us; speedup vs baseline: 4.8047x; 4.8047x over previous
//
#include <hip/hip_runtime.h>
#include <hip/hip_cooperative_groups.h>
#include <stdint.h>
#include <math.h>

namespace cg = cooperative_groups;

// Problem constants (fixed by setup_inputs: B=4, N=4096, H=2048, L=64, K=8)
constexpr int H     = 2048;
constexpr int L     = 64;
constexpr int K_SEL = 8;
constexpr int TM    = 32;     // rows per block (phase 1); 512 blocks * 32 = 16384 rows
constexpr int NBLK  = 512;    // 2 blocks/CU co-resident (128 thr) -> 4 waves/CU
// bf16 hi/lo split noise sigma ~1e-5 per logit. EPS = 2e-4 = 20 sigma;
// n_fix ~ 131072*EPS/0.071 ~ 370 rows (validated r4: passed with this gate).
constexpr float EPS_GAP = 2e-4f;

// ws carve (byte offsets)
constexpr size_t WSB_COUNTS = 0;        // uint[65]
constexpr size_t WSB_NFIX   = 512;      // uint
constexpr size_t WSB_LIST   = 1024;     // uint[16384]
constexpr size_t WSB_WT     = 66560;    // float[2048*64]   Wt[k][l] (fixup)
constexpr size_t WSB_WHI    = 590848;   // ushort[64*2048]  bf16-hi, [l][k]
constexpr size_t WSB_WLO    = 852992;   // ushort[64*2048]  bf16-lo, [l][k]

typedef __attribute__((ext_vector_type(8))) short bf16x8;   // 8 bf16 (4 VGPRs)
typedef __attribute__((ext_vector_type(4))) float f32x4;    // MFMA C/D frag

// A-side hi/lo split: f = hi(bf16-trunc) + lo(bf16-trunc of residual) + O(2^-16 f)
__device__ __forceinline__ void split_a(const float4& a0, const float4& a1,
                                        bf16x8& ah, bf16x8& al)
{
    float f[8] = {a0.x, a0.y, a0.z, a0.w, a1.x, a1.y, a1.z, a1.w};
    #pragma unroll
    for (int i = 0; i < 8; ++i) {
        unsigned int u = __float_as_uint(f[i]);
        ah[i] = (short)(u >> 16);
        al[i] = (short)(__float_as_uint(f[i] - __uint_as_float(u & 0xffff0000u)) >> 16);
    }
}

__device__ __forceinline__ void load_b(const unsigned short* __restrict__ bhb,
                                       const unsigned short* __restrict__ blb,
                                       int k, bf16x8 (&BH)[4], bf16x8 (&BL)[4])
{
    #pragma unroll
    for (int tl = 0; tl < 4; ++tl) {          // unroll-constant tl -> register-resident
        BH[tl] = *(const bf16x8*)(bhb + (size_t)tl * 16 * H + k);
        BL[tl] = *(const bf16x8*)(blb + (size_t)tl * 16 * H + k);
    }
}

__device__ __forceinline__ void mfma3(const bf16x8& ah, const bf16x8& al,
                                      const bf16x8 (&BH)[4], const bf16x8 (&BL)[4],
                                      f32x4 (&acc)[4])
{
    // 3-product split GEMM (drop lo*lo); 4 independent acc chains give ILP
    #pragma unroll
    for (int tl = 0; tl < 4; ++tl) {
        acc[tl] = __builtin_amdgcn_mfma_f32_16x16x32_bf16(ah, BH[tl], acc[tl], 0, 0, 0);
        acc[tl] = __builtin_amdgcn_mfma_f32_16x16x32_bf16(al, BH[tl], acc[tl], 0, 0, 0);
        acc[tl] = __builtin_amdgcn_mfma_f32_16x16x32_bf16(ah, BL[tl], acc[tl], 0, 0, 0);
    }
}

// Single cooperative kernel:
//   phase 0: W -> Whi/Wlo (bf16 split) + Wt (fp32 transpose); zero counters
//   phase 1: bf16-split MFMA GEMM (wave = 16 rows x 64 experts) + top-9 select
//   phase 2: fp64 exact fixup for gap-flagged rows
//   phase 3: loss scalars
__global__ __launch_bounds__(128)
void router_coop(const float* __restrict__ x, const float* __restrict__ Wr,
                 const float* __restrict__ bias, const unsigned char* __restrict__ am,
                 unsigned short* __restrict__ Whi, unsigned short* __restrict__ Wlo,
                 float* __restrict__ Wt,
                 float* __restrict__ out_sel, float* __restrict__ out_probs,
                 unsigned int* __restrict__ counts, unsigned int* __restrict__ nfix,
                 unsigned int* __restrict__ list, float* __restrict__ out_scal)
{
    cg::grid_group grid = cg::this_grid();

    __shared__ float lg[TM][L + 1];
    __shared__ float bs[L];
    __shared__ unsigned int cnt[L + 1];

    const int t = threadIdx.x, b = blockIdx.x;
    const int lane = t & 63, w = t >> 6;          // 2 waves/block
    const int R0 = b * TM;

    // ---------------- phase 0: weight prep + counter zero ----------------
    {
        const int e0 = (b * 128 + t) * 2;         // 2 consecutive W elements/thread
        const int l  = e0 >> 11;                  // row of Wr (expert)
        const int k  = e0 & 2047;
        float2 v = *(const float2*)(Wr + e0);     // coalesced
        unsigned int ux = __float_as_uint(v.x), uy = __float_as_uint(v.y);
        unsigned short hx = (unsigned short)(ux >> 16);
        unsigned short hy = (unsigned short)(uy >> 16);
        unsigned short sx = (unsigned short)(__float_as_uint(v.x - __uint_as_float(ux & 0xffff0000u)) >> 16);
        unsigned short sy = (unsigned short)(__float_as_uint(v.y - __uint_as_float(uy & 0xffff0000u)) >> 16);
        *(ushort2*)(Whi + e0) = make_ushort2(hx, hy);   // coalesced
        *(ushort2*)(Wlo + e0) = make_ushort2(sx, sy);
        Wt[(size_t)(k + 0) * L + l] = v.x;              // scattered; W is 512 KB, L2 absorbs
        Wt[(size_t)(k + 1) * L + l] = v.y;
        if (b == 0) {
            if (t < L + 1) counts[t] = 0u;
            if (t == L + 1) *nfix = 0u;
        }
    }
    __threadfence();
    grid.sync();

    // ---------------- phase 1: GEMM + select ----------------
    if (t < L) bs[t] = bias[t];
    if (t < L + 1) cnt[t] = 0;

    {
        const int m  = lane & 15;          // A row within 16-tile / B expert column
        const int kq = (lane >> 4) * 8;    // lane k offset within 32-k step
        const float* xrow = x + (size_t)(R0 + 16 * w + m) * H + kq;
        const unsigned short* bhb = Whi + (size_t)m * H + kq;
        const unsigned short* blb = Wlo + (size_t)m * H + kq;

        f32x4 acc[4];
        #pragma unroll
        for (int tl = 0; tl < 4; ++tl)
            #pragma unroll
            for (int r = 0; r < 4; ++r) acc[tl][r] = 0.f;

        // Explicitly-named double buffers; ALL indices unroll-constant ->
        // register-resident (r4 lesson: [s&1] indexing demoted these to scratch,
        // 22.6 MB WRITE_SIZE, 2543 us).
        float4 A0a, A1a, A0b, A1b;
        bf16x8 BHa[4], BLa[4], BHb[4], BLb[4];
        bf16x8 ah, al;

        A0a = *(const float4*)(xrow);
        A1a = *(const float4*)(xrow + 4);
        load_b(bhb, blb, 0, BHa, BLa);

        for (int s = 0; s < H / 32; s += 2) {
            const int k1 = (s + 1) * 32;                       // s <= 62 -> k1 valid
            A0b = *(const float4*)(xrow + k1);
            A1b = *(const float4*)(xrow + k1 + 4);
            load_b(bhb, blb, k1, BHb, BLb);

            split_a(A0a, A1a, ah, al);
            mfma3(ah, al, BHa, BLa, acc);

            const int k2 = (s + 2 < H / 32) ? (s + 2) * 32 : k1;   // clamp: dead load on last iter
            A0a = *(const float4*)(xrow + k2);
            A1a = *(const float4*)(xrow + k2 + 4);
            load_b(bhb, blb, k2, BHa, BLa);

            split_a(A0b, A1b, ah, al);
            mfma3(ah, al, BHb, BLb, acc);
        }

        // C/D layout: col = lane&15, row = (lane>>4)*4 + reg  [m89-verified, r4-validated]
        #pragma unroll
        for (int tl = 0; tl < 4; ++tl)
            #pragma unroll
            for (int r = 0; r < 4; ++r)
                lg[16 * w + (lane >> 4) * 4 + r][16 * tl + (lane & 15)] = acc[tl][r];
    }
    __syncthreads();

    if (t < TM) {
        const int grow = R0 + t;
        unsigned long long chosen = 0ull;
        int idx[K_SEL];
        float prev = 0.f, gmin = INFINITY;
        for (int kk = 0; kk < K_SEL + 1; ++kk) {   // 9 rounds: need gap rank8->rank9
            float best = -INFINITY; int bi = 0;
            for (int l = 0; l < L; ++l) {
                if ((chosen >> l) & 1ull) continue;
                float v = lg[t][l] + bs[l];        // strict '>' == jax top_k tie-break
                if (v > best) { best = v; bi = l; }
            }
            if (kk > 0) gmin = fminf(gmin, prev - best);
            prev = best;
            if (kk < K_SEL) { chosen |= 1ull << bi; idx[kk] = bi; }
        }

        if (gmin < EPS_GAP) {
            unsigned int p = atomicAdd(nfix, 1u);
            __hip_atomic_store(&list[p], (unsigned int)grow,
                               __ATOMIC_RELAXED, __HIP_MEMORY_SCOPE_AGENT);
        } else {
            float zv[K_SEL], mx = -INFINITY;
            #pragma unroll
            for (int kk = 0; kk < K_SEL; ++kk) { zv[kk] = lg[t][idx[kk]]; mx = fmaxf(mx, zv[kk]); }
            float e[K_SEL], ssum = 0.f;
            #pragma unroll
            for (int kk = 0; kk < K_SEL; ++kk) { e[kk] = expf(zv[kk] - mx); ssum += e[kk]; }
            #pragma unroll
            for (int kk = 0; kk < K_SEL; ++kk) {
                out_sel[(size_t)grow * K_SEL + kk]   = (float)idx[kk];
                out_probs[(size_t)grow * K_SEL + kk] = e[kk] / ssum;
            }
            if (am[grow]) {
                atomicAdd(&cnt[L], 1u);
                #pragma unroll
                for (int kk = 0; kk < K_SEL; ++kk) atomicAdd(&cnt[idx[kk]], 1u);
            }
        }
    }
    __syncthreads();
    if (t < L + 1 && cnt[t]) atomicAdd(&counts[t], cnt[t]);

    __threadfence();
    grid.sync();

    // ---------------- phase 2: fp64 fixup (wave-per-row) ----------------
    {
        const int wid = (b << 1) | w;
        const int nw  = NBLK * 2;
        const int n   = (int)__hip_atomic_load(nfix, __ATOMIC_RELAXED, __HIP_MEMORY_SCOPE_AGENT);
        const double blv = (double)bias[lane];

        for (int i = wid; i < n; i += nw) {
            const int row = (int)__hip_atomic_load(&list[i], __ATOMIC_RELAXED,
                                                   __HIP_MEMORY_SCOPE_AGENT);
            const float* xr = x + (size_t)row * H;
            double A0 = 0.0, A1 = 0.0, A2 = 0.0, A3 = 0.0;
            #pragma unroll 2
            for (int k = 0; k < H; k += 16) {
                float4 x0 = *(const float4*)(xr + k);
                float4 x1 = *(const float4*)(xr + k + 4);
                float4 x2 = *(const float4*)(xr + k + 8);
                float4 x3 = *(const float4*)(xr + k + 12);
                A0 = fma((double)x0.x, (double)Wt[(k +  0) * L + lane], A0);
                A1 = fma((double)x0.y, (double)Wt[(k +  1) * L + lane], A1);
                A2 = fma((double)x0.z, (double)Wt[(k +  2) * L + lane], A2);
                A3 = fma((double)x0.w, (double)Wt[(k +  3) * L + lane], A3);
                A0 = fma((double)x1.x, (double)Wt[(k +  4) * L + lane], A0);
                A1 = fma((double)x1.y, (double)Wt[(k +  5) * L + lane], A1);
                A2 = fma((double)x1.z, (double)Wt[(k +  6) * L + lane], A2);
                A3 = fma((double)x1.w, (double)Wt[(k +  7) * L + lane], A3);
                A0 = fma((double)x2.x, (double)Wt[(k +  8) * L + lane], A0);
                A1 = fma((double)x2.y, (double)Wt[(k +  9) * L + lane], A1);
                A2 = fma((double)x2.z, (double)Wt[(k + 10) * L + lane], A2);
                A3 = fma((double)x2.w, (double)Wt[(k + 11) * L + lane], A3);
                A0 = fma((double)x3.x, (double)Wt[(k + 12) * L + lane], A0);
                A1 = fma((double)x3.y, (double)Wt[(k + 13) * L + lane], A1);
                A2 = fma((double)x3.z, (double)Wt[(k + 14) * L + lane], A2);
                A3 = fma((double)x3.w, (double)Wt[(k + 15) * L + lane], A3);
            }
            double accd = (A0 + A1) + (A2 + A3);

            double v = accd + blv;
            int    widx[K_SEL];
            double wlog[K_SEL];
            #pragma unroll
            for (int kk = 0; kk < K_SEL; ++kk) {
                double mv = v; int mi = lane;
                #pragma unroll
                for (int off = 32; off; off >>= 1) {
                    double ov = __shfl_xor(mv, off);
                    int    oi = __shfl_xor(mi, off);
                    if (ov > mv || (ov == mv && oi < mi)) { mv = ov; mi = oi; }
                }
                widx[kk] = mi;
                wlog[kk] = __shfl(accd, mi);
                if (lane == mi) v = -INFINITY;
            }

            double mx = -INFINITY;
            #pragma unroll
            for (int kk = 0; kk < K_SEL; ++kk) mx = fmax(mx, wlog[kk]);
            float e[K_SEL], ssum = 0.f;
            #pragma unroll
            for (int kk = 0; kk < K_SEL; ++kk) { e[kk] = expf((float)(wlog[kk] - mx)); ssum += e[kk]; }

            if (lane < K_SEL) {
                out_sel[(size_t)row * K_SEL + lane]   = (float)widx[lane];
                out_probs[(size_t)row * K_SEL + lane] = e[lane] / ssum;
            }
            if (am[row]) {
                if (lane < K_SEL)  atomicAdd(&counts[widx[lane]], 1u);
                if (lane == K_SEL) atomicAdd(&counts[L], 1u);
            }
        }
    }

    __threadfence();
    grid.sync();

    // ---------------- phase 3: finalize (block 0, wave 0) ----------------
    if (b == 0 && w == 0) {
        unsigned int cl = __hip_atomic_load(&counts[lane], __ATOMIC_RELAXED,
                                            __HIP_MEMORY_SCOPE_AGENT);
        unsigned int ca = __hip_atomic_load(&counts[L], __ATOMIC_RELAXED,
                                            __HIP_MEMORY_SCOPE_AGENT);
        const float denom = (float)ca * (float)K_SEL;
        const float f = (float)cl / denom;
        float d  = f - 1.0f / (float)L;
        float sq = d * d;
        #pragma unroll
        for (int o = 32; o > 0; o >>= 1) {
            sq += __shfl_down(sq, o);
            d = fmaxf(d, __shfl_down(d, o));
        }
        if (lane == 0) {
            out_scal[0] = (float)L * sq;  // load_balance_loss
            out_scal[1] = (float)L * d;   // max_vio
        }
    }
}

extern "C" void kernel_launch(void* const* d_in, const int* in_sizes, int n_in,
                              void* d_out, int out_size, void* d_ws, size_t ws_size,
                              hipStream_t stream)
{
    const float* x          = (const float*)d_in[0];
    const float* Wr         = (const float*)d_in[1];
    const float* bias       = (const float*)d_in[2];
    const unsigned char* am = (const unsigned char*)d_in[3];
    float* out = (float*)d_out;
    char*  wsb = (char*)d_ws;

    const int rows = in_sizes[3];  // B*N = 16384

    float* out_sel   = out;
    float* out_probs = out + (size_t)rows * K_SEL;
    float* out_scal  = out + (size_t)rows * K_SEL * 2;

    unsigned int*   counts = (unsigned int*)(wsb + WSB_COUNTS);
    unsigned int*   nfix   = (unsigned int*)(wsb + WSB_NFIX);
    unsigned int*   list   = (unsigned int*)(wsb + WSB_LIST);
    float*          Wt     = (float*)(wsb + WSB_WT);
    unsigned short* Whi    = (unsigned short*)(wsb + WSB_WHI);
    unsigned short* Wlo    = (unsigned short*)(wsb + WSB_WLO);

    void* args[] = { (void*)&x, (void*)&Wr, (void*)&bias, (void*)&am,
                     (void*)&Whi, (void*)&Wlo, (void*)&Wt,
                     (void*)&out_sel, (void*)&out_probs, (void*)&counts,
                     (void*)&nfix, (void*)&list, (void*)&out_scal };
    hipLaunchCooperativeKernel((void*)router_coop, dim3(NBLK), dim3(128), args, 0, stream);
}